// Round 4
// baseline (122.051 us; speedup 1.0000x reference)
//
#include <hip/hip_runtime.h>

// VQ-VAE vector quantization via bf16-split MFMA (x=xh+xl, c=ch+cl; score =
// xh.ch + xh.cl + xl.ch - 0.5||c||^2, error ~2^-18 relative).
// N = 131072 queries (D=64), up to 1024 codes.
// Round 4: NO LDS/barriers in K-loop. B fragments come straight from L2 via
// coalesced global_load_dwordx4 (packed [chunk][granule][code] layout, 256KB,
// L2-resident). Each wave free-runs its own load->MFMA->argmax pipeline.
// ws layout (floats): [0] loss, [1024..2047] nhn=-0.5||c||^2, [2048..3071] counts,
//                     [4096..69631] packed bf16 code granules.

typedef __attribute__((ext_vector_type(8))) short short8;
typedef __attribute__((ext_vector_type(16))) float f32x16;

#define PACKED_OFF 4096

__device__ __forceinline__ unsigned short bf16_rne(float v, float& rest) {
  const unsigned u = __float_as_uint(v);
  const unsigned r = u + 0x7fffu + ((u >> 16) & 1u);
  const unsigned short h = (unsigned short)(r >> 16);
  rest = v - __uint_as_float((unsigned)h << 16);
  return h;
}

// Pre-split codes into bf16 hi/lo granules + norms; zero accumulators.
// Granule g of code c (16B = 8 bf16): g<8 -> hi dims g*8..g*8+7; g>=8 -> lo.
// Packed addr (floats): PACKED_OFF + (c>>6)*4096 + g*256 + (c&63)*4.
__global__ void vq_pack(const float* __restrict__ cb0, const float* __restrict__ cb1,
                        float* __restrict__ ws) {
  const int c = blockIdx.x * 256 + threadIdx.x;  // 0..1023
  ws[2048 + c] = 0.0f;                           // counts
  if (c == 0) ws[0] = 0.0f;                      // loss
  const float* row = (c < 512) ? (cb0 + (size_t)c * 64) : (cb1 + (size_t)(c - 512) * 64);
  float v[64];
  float nrm = 0.f;
#pragma unroll
  for (int d = 0; d < 64; d += 4) {
    const float4 f = *(const float4*)(row + d);
    v[d] = f.x; v[d + 1] = f.y; v[d + 2] = f.z; v[d + 3] = f.w;
    nrm += f.x * f.x + f.y * f.y + f.z * f.z + f.w * f.w;
  }
  ws[1024 + c] = -0.5f * nrm;
  unsigned short hi[64], lo[64];
#pragma unroll
  for (int d = 0; d < 64; ++d) {
    float rest, dump;
    hi[d] = bf16_rne(v[d], rest);
    lo[d] = bf16_rne(rest, dump);
  }
  float* pbase = ws + PACKED_OFF + (size_t)(c >> 6) * 4096 + (c & 63) * 4;
#pragma unroll
  for (int g = 0; g < 16; ++g) {
    short8 gr;
#pragma unroll
    for (int e = 0; e < 8; ++e)
      gr[e] = (short)((g < 8) ? hi[g * 8 + e] : lo[(g - 8) * 8 + e]);
    *(short8*)(pbase + g * 256) = gr;
  }
}

__global__ __launch_bounds__(256, 4) void vq_main(
    const float* __restrict__ xin, const float* __restrict__ cb0,
    const float* __restrict__ cb1, const int* __restrict__ idxp,
    float* __restrict__ out, float* __restrict__ ws) {
  __shared__ float xfp[64 * 128];  // x tile [d][q]; reused as qidx after K-loop
  const int tid = threadIdx.x;
  const int w = tid >> 6;      // wave 0..3, owns q rows w*32..+31
  const int l = tid & 63;
  const int half = l >> 5;
  const int col = l & 31;
  const int blk = blockIdx.x;  // 1024 blocks x 128 q
  const int bb = blk >> 5;
  const int hw0 = (blk & 31) << 7;
  const int nch = (*idxp == 0) ? 8 : 16;
  const float* nhn = ws + 1024;
  const char* pk = (const char*)(ws + PACKED_OFF);
  float* counts = ws + 2048;

  // ---- stage x fp32 tile [d=64][q=128] into LDS (coalesced both sides)
  {
    const int qg = (tid & 31) << 2;
    const int dsub = tid >> 5;  // 0..7
#pragma unroll
    for (int p = 0; p < 8; ++p) {
      const int d = p * 8 + dsub;
      const float4 f = *(const float4*)(xin + (((size_t)(bb * 64 + d)) << 12) + hw0 + qg);
      *(float4*)(xfp + d * 128 + qg) = f;
    }
  }
  __syncthreads();

  // ---- extract A fragments (xh, xl) into registers + ||x||^2 per q-row
  short8 xh[4], xl[4];
  float xx;
  {
    const int qloc = w * 32 + col;
    float s = 0.f;
#pragma unroll
    for (int kf = 0; kf < 4; ++kf) {
#pragma unroll
      for (int j = 0; j < 8; ++j) {
        const int d = kf * 16 + half * 8 + j;
        const float v = xfp[d * 128 + qloc];
        float rest, dump;
        xh[kf][j] = (short)bf16_rne(v, rest);
        xl[kf][j] = (short)bf16_rne(rest, dump);
        s += v * v;
      }
    }
    s += __shfl_xor(s, 32);  // lanes l, l^32 hold same q, complementary d
    xx = s;
  }
  __syncthreads();  // xfp dead; epilogue reuses it for qidx

  float best[16];
  int meta[16];
#pragma unroll
  for (int r = 0; r < 16; ++r) { best[r] = -3.4e38f; meta[r] = 0; }

  // Per-lane byte offset within a chunk: granule parity by half + col.
  // Fragment (kf, hi, n): chunk_base + kf*2048 + n*512 + lbase; lo: +8192.
  const int lbase = half * 1024 + col * 16;

#pragma unroll 2
  for (int ch = 0; ch < nch; ++ch) {
    const char* cbase = pk + (size_t)ch * 16384 + lbase;

    // acc starts at -0.5||c||^2 (C layout: col = lane&31 for every reg)
    f32x16 acc[2];
    {
      const float nh0 = nhn[ch * 64 + col];
      const float nh1 = nhn[ch * 64 + 32 + col];
#pragma unroll
      for (int r = 0; r < 16; ++r) { acc[0][r] = nh0; acc[1][r] = nh1; }
    }

#pragma unroll
    for (int kf = 0; kf < 4; ++kf) {
      const char* p = cbase + kf * 2048;
      const short8 bh0 = *(const short8*)(p);
      const short8 bh1 = *(const short8*)(p + 512);
      const short8 bl0 = *(const short8*)(p + 8192);
      const short8 bl1 = *(const short8*)(p + 8192 + 512);
      acc[0] = __builtin_amdgcn_mfma_f32_32x32x16_bf16(xh[kf], bh0, acc[0], 0, 0, 0);
      acc[1] = __builtin_amdgcn_mfma_f32_32x32x16_bf16(xh[kf], bh1, acc[1], 0, 0, 0);
      acc[0] = __builtin_amdgcn_mfma_f32_32x32x16_bf16(xh[kf], bl0, acc[0], 0, 0, 0);
      acc[1] = __builtin_amdgcn_mfma_f32_32x32x16_bf16(xh[kf], bl1, acc[1], 0, 0, 0);
      acc[0] = __builtin_amdgcn_mfma_f32_32x32x16_bf16(xl[kf], bh0, acc[0], 0, 0, 0);
      acc[1] = __builtin_amdgcn_mfma_f32_32x32x16_bf16(xl[kf], bh1, acc[1], 0, 0, 0);
    }

    // ---- running argmax; meta = ch*2 + nf (col implicit)
    const int mb = ch * 2;
#pragma unroll
    for (int r = 0; r < 16; ++r) {
      const float s0 = acc[0][r];
      const float s1 = acc[1][r];
      const bool t1 = s1 > s0;  // tie -> nf=0 (smaller index)
      const float v = t1 ? s1 : s0;
      const int mt = mb + (t1 ? 1 : 0);
      if (v > best[r]) { best[r] = v; meta[r] = mt; }  // tie -> earlier chunk
    }
  }

  // ---- cross-lane argmax reduce (within 32-lane half), first-index ties
  int* qidx = (int*)xfp;
  float ls = 0.f;
#pragma unroll
  for (int r = 0; r < 16; ++r) {
    float v = best[r];
    int idx = meta[r] * 32 + col;
#pragma unroll
    for (int mk = 1; mk < 32; mk <<= 1) {
      const float ov = __shfl_xor(v, mk);
      const int oi = __shfl_xor(idx, mk);
      if (ov > v || (ov == v && oi < idx)) { v = ov; idx = oi; }
    }
    const int row = (r & 3) + 8 * (r >> 2) + 4 * half;  // C layout row
    if (col == row) {
      ls += xx - 2.0f * v;  // ||x||^2 - 2(x.c* - 0.5||c*||^2) = ||x-c*||^2
      qidx[w * 32 + row] = idx;
    }
  }
#pragma unroll
  for (int mk = 1; mk < 64; mk <<= 1) ls += __shfl_xor(ls, mk);
  if (l == 0) atomicAdd(ws, ls);
  __syncthreads();

  // ---- histogram + quantized output (NCHW, coalesced stores; codes L2-hot)
  const int qloc = tid & 127;
  const int dh = tid >> 7;  // 0/1: which 32-d half this thread writes
  const int ci = qidx[qloc];
  if (tid < 128) atomicAdd(&counts[ci], 1.0f);
  const float* crow = (ci < 512) ? (cb0 + (size_t)ci * 64) : (cb1 + (size_t)(ci - 512) * 64);
  float cv[32];
#pragma unroll
  for (int d = 0; d < 32; d += 4) {
    const float4 f = *(const float4*)(crow + dh * 32 + d);
    cv[d] = f.x; cv[d + 1] = f.y; cv[d + 2] = f.z; cv[d + 3] = f.w;
  }
  float* ob = out + (((size_t)(bb * 64 + dh * 32)) << 12) + hw0 + qloc;
#pragma unroll
  for (int d = 0; d < 32; ++d) ob[(size_t)d << 12] = cv[d];
}

__global__ void vq_final(const float* __restrict__ ws, float* __restrict__ out) {
  __shared__ float sred[256];
  const int t = threadIdx.x;
  float h = 0.f;
#pragma unroll
  for (int i = t; i < 1024; i += 256) {
    const float avg = ws[2048 + i] * (1.0f / 131072.0f);
    h += avg * logf(avg + 1e-10f);
  }
  sred[t] = h;
  __syncthreads();
  for (int s2 = 128; s2 > 0; s2 >>= 1) {
    if (t < s2) sred[t] += sred[t + s2];
    __syncthreads();
  }
  if (t == 0) {
    out[8388608] = 1.25f * ws[0] * (1.0f / 8388608.0f);
    out[8388609] = expf(-sred[0]);
  }
}

extern "C" void kernel_launch(void* const* d_in, const int* in_sizes, int n_in,
                              void* d_out, int out_size, void* d_ws, size_t ws_size,
                              hipStream_t stream) {
  (void)in_sizes; (void)n_in; (void)out_size; (void)ws_size;
  const float* xin = (const float*)d_in[0];
  const float* cb0 = (const float*)d_in[1];
  const float* cb1 = (const float*)d_in[2];
  const int* idxp = (const int*)d_in[3];
  float* out = (float*)d_out;
  float* ws = (float*)d_ws;

  vq_pack<<<4, 256, 0, stream>>>(cb0, cb1, ws);
  vq_main<<<1024, 256, 0, stream>>>(xin, cb0, cb1, idxp, out, ws);
  vq_final<<<1, 256, 0, stream>>>(ws, out);
}

// Round 5
// 121.286 us; speedup vs baseline: 1.0063x; 1.0063x over previous
//
#include <hip/hip_runtime.h>

// VQ-VAE vector quantization via bf16-split MFMA (x=xh+xl, c=ch+cl; score =
// xh.ch + xh.cl + xl.ch - 0.5||c||^2, error ~2^-18 relative).
// N = 131072 queries (D=64), up to 1024 codes.
// Round 5: barrier-free K-loop + EXPLICIT register double-buffer prefetch
// (two named 16-fragment buffers, chunk-pair unroll), launch_bounds(256,2)
// so the compiler has VGPRs to hold loads in flight. Argmax packs candidate
// id into score mantissa LSBs (<=2^-18 perturbation) -> fmax-only updates.
// ws layout (floats): [0] loss, [1024..2047] nhn=-0.5||c||^2, [2048..3071] counts,
//                     [4096..69631] packed bf16 code granules.

typedef __attribute__((ext_vector_type(8))) short short8;
typedef __attribute__((ext_vector_type(16))) float f32x16;

#define PACKED_OFF 4096

__device__ __forceinline__ unsigned short bf16_rne(float v, float& rest) {
  const unsigned u = __float_as_uint(v);
  const unsigned r = u + 0x7fffu + ((u >> 16) & 1u);
  const unsigned short h = (unsigned short)(r >> 16);
  rest = v - __uint_as_float((unsigned)h << 16);
  return h;
}

// Pre-split codes into bf16 hi/lo granules + norms; zero accumulators.
// Granule g of code c (16B = 8 bf16): g<8 -> hi dims g*8..g*8+7; g>=8 -> lo.
// Packed addr (floats): PACKED_OFF + (c>>6)*4096 + g*256 + (c&63)*4.
__global__ void vq_pack(const float* __restrict__ cb0, const float* __restrict__ cb1,
                        float* __restrict__ ws) {
  const int c = blockIdx.x * 256 + threadIdx.x;  // 0..1023
  ws[2048 + c] = 0.0f;                           // counts
  if (c == 0) ws[0] = 0.0f;                      // loss
  const float* row = (c < 512) ? (cb0 + (size_t)c * 64) : (cb1 + (size_t)(c - 512) * 64);
  float v[64];
  float nrm = 0.f;
#pragma unroll
  for (int d = 0; d < 64; d += 4) {
    const float4 f = *(const float4*)(row + d);
    v[d] = f.x; v[d + 1] = f.y; v[d + 2] = f.z; v[d + 3] = f.w;
    nrm += f.x * f.x + f.y * f.y + f.z * f.z + f.w * f.w;
  }
  ws[1024 + c] = -0.5f * nrm;
  unsigned short hi[64], lo[64];
#pragma unroll
  for (int d = 0; d < 64; ++d) {
    float rest, dump;
    hi[d] = bf16_rne(v[d], rest);
    lo[d] = bf16_rne(rest, dump);
  }
  float* pbase = ws + PACKED_OFF + (size_t)(c >> 6) * 4096 + (c & 63) * 4;
#pragma unroll
  for (int g = 0; g < 16; ++g) {
    short8 gr;
#pragma unroll
    for (int e = 0; e < 8; ++e)
      gr[e] = (short)((g < 8) ? hi[g * 8 + e] : lo[(g - 8) * 8 + e]);
    *(short8*)(pbase + g * 256) = gr;
  }
}

__global__ __launch_bounds__(256, 2) void vq_main(
    const float* __restrict__ xin, const float* __restrict__ cb0,
    const float* __restrict__ cb1, const int* __restrict__ idxp,
    float* __restrict__ out, float* __restrict__ ws) {
  __shared__ float xfp[64 * 128];  // x tile [d][q]; reused as qidx after K-loop
  const int tid = threadIdx.x;
  const int w = tid >> 6;      // wave 0..3, owns q rows w*32..+31
  const int l = tid & 63;
  const int half = l >> 5;
  const int col = l & 31;
  const int blk = blockIdx.x;  // 1024 blocks x 128 q
  const int bb = blk >> 5;
  const int hw0 = (blk & 31) << 7;
  const int nch = (*idxp == 0) ? 8 : 16;
  const float* nhn = ws + 1024;
  float* counts = ws + 2048;

  // ---- stage x fp32 tile [d=64][q=128] into LDS (coalesced both sides)
  {
    const int qg = (tid & 31) << 2;
    const int dsub = tid >> 5;  // 0..7
#pragma unroll
    for (int p = 0; p < 8; ++p) {
      const int d = p * 8 + dsub;
      const float4 f = *(const float4*)(xin + (((size_t)(bb * 64 + d)) << 12) + hw0 + qg);
      *(float4*)(xfp + d * 128 + qg) = f;
    }
  }
  __syncthreads();

  // ---- extract A fragments (xh, xl) into registers + ||x||^2 per q-row
  short8 xh[4], xl[4];
  float xx;
  {
    const int qloc = w * 32 + col;
    float s = 0.f;
#pragma unroll
    for (int kf = 0; kf < 4; ++kf) {
#pragma unroll
      for (int j = 0; j < 8; ++j) {
        const int d = kf * 16 + half * 8 + j;
        const float v = xfp[d * 128 + qloc];
        float rest, dump;
        xh[kf][j] = (short)bf16_rne(v, rest);
        xl[kf][j] = (short)bf16_rne(rest, dump);
        s += v * v;
      }
    }
    s += __shfl_xor(s, 32);  // lanes l, l^32 hold same q, complementary d
    xx = s;
  }
  __syncthreads();  // xfp dead; epilogue reuses it for qidx

  // best[r]: score with low 5 mantissa bits replaced by (31 - (ch*2+n));
  // fmax then prefers smaller code index on (near-)ties. <=2^-18 perturbation.
  float best[16];
#pragma unroll
  for (int r = 0; r < 16; ++r) best[r] = -3.4e38f;

  // Per-lane byte offset within a chunk; fragment (kf,n,hi): kf*2048 + n*512
  // (+8192 for lo) + half*1024 + col*16.
  const char* pkl = (const char*)(ws + PACKED_OFF) + half * 1024 + col * 16;

  auto loadChunk = [&](int ch, short8(&B)[16], float& nh0, float& nh1) {
    const char* p = pkl + (size_t)ch * 16384;
#pragma unroll
    for (int kf = 0; kf < 4; ++kf) {
      B[kf * 4 + 0] = *(const short8*)(p + kf * 2048);
      B[kf * 4 + 1] = *(const short8*)(p + kf * 2048 + 512);
      B[kf * 4 + 2] = *(const short8*)(p + kf * 2048 + 8192);
      B[kf * 4 + 3] = *(const short8*)(p + kf * 2048 + 8704);
    }
    nh0 = nhn[ch * 64 + col];
    nh1 = nhn[ch * 64 + 32 + col];
  };

  auto compute = [&](const short8(&B)[16], int ch, float nh0, float nh1) {
    f32x16 a0, a1;
#pragma unroll
    for (int r = 0; r < 16; ++r) { a0[r] = nh0; a1[r] = nh1; }
    __builtin_amdgcn_s_setprio(1);
#pragma unroll
    for (int kf = 0; kf < 4; ++kf) {
      a0 = __builtin_amdgcn_mfma_f32_32x32x16_bf16(xh[kf], B[kf * 4 + 0], a0, 0, 0, 0);
      a1 = __builtin_amdgcn_mfma_f32_32x32x16_bf16(xh[kf], B[kf * 4 + 1], a1, 0, 0, 0);
      a0 = __builtin_amdgcn_mfma_f32_32x32x16_bf16(xh[kf], B[kf * 4 + 2], a0, 0, 0, 0);
      a1 = __builtin_amdgcn_mfma_f32_32x32x16_bf16(xh[kf], B[kf * 4 + 3], a1, 0, 0, 0);
      a0 = __builtin_amdgcn_mfma_f32_32x32x16_bf16(xl[kf], B[kf * 4 + 0], a0, 0, 0, 0);
      a1 = __builtin_amdgcn_mfma_f32_32x32x16_bf16(xl[kf], B[kf * 4 + 1], a1, 0, 0, 0);
    }
    __builtin_amdgcn_s_setprio(0);
    const unsigned sid0 = (unsigned)(31 - 2 * ch);  // n=0: higher -> preferred
    const unsigned sid1 = (unsigned)(30 - 2 * ch);
#pragma unroll
    for (int r = 0; r < 16; ++r) {
      const unsigned p0 = (__float_as_uint(a0[r]) & 0xFFFFFFE0u) | sid0;
      const unsigned p1 = (__float_as_uint(a1[r]) & 0xFFFFFFE0u) | sid1;
      best[r] = fmaxf(best[r], fmaxf(__uint_as_float(p0), __uint_as_float(p1)));
    }
  };

  short8 B0[16], B1[16];
  float nhA0, nhA1, nhB0, nhB1;
  loadChunk(0, B0, nhA0, nhA1);
  const int npairs = nch >> 1;
  for (int pr = 0; pr < npairs; ++pr) {
    const int ch0 = pr * 2;
    loadChunk(ch0 + 1, B1, nhB0, nhB1);           // prefetch odd chunk
    compute(B0, ch0, nhA0, nhA1);                 // covers B1 latency
    loadChunk(ch0 + 2 < nch ? ch0 + 2 : 0, B0, nhA0, nhA1);  // prefetch next pair
    compute(B1, ch0 + 1, nhB0, nhB1);             // covers B0 latency
  }

  // ---- cross-lane argmax reduce (within 32-lane half), first-index ties
  int* qidx = (int*)xfp;
  float ls = 0.f;
#pragma unroll
  for (int r = 0; r < 16; ++r) {
    float v = best[r];
    int idx = (int)(31u - (__float_as_uint(v) & 31u)) * 32 + col;
#pragma unroll
    for (int mk = 1; mk < 32; mk <<= 1) {
      const float ov = __shfl_xor(v, mk);
      const int oi = __shfl_xor(idx, mk);
      if (ov > v || (ov == v && oi < idx)) { v = ov; idx = oi; }
    }
    const int row = (r & 3) + 8 * (r >> 2) + 4 * half;  // C layout row
    if (col == row) {
      const float vc = __uint_as_float(__float_as_uint(v) & 0xFFFFFFE0u);
      ls += xx - 2.0f * vc;  // ||x||^2 - 2(x.c* - 0.5||c*||^2) = ||x-c*||^2
      qidx[w * 32 + row] = idx;
    }
  }
#pragma unroll
  for (int mk = 1; mk < 64; mk <<= 1) ls += __shfl_xor(ls, mk);
  if (l == 0) atomicAdd(ws, ls);
  __syncthreads();

  // ---- histogram + quantized output (NCHW, coalesced stores; codes L2-hot)
  const int qloc = tid & 127;
  const int dh = tid >> 7;  // 0/1: which 32-d half this thread writes
  const int ci = qidx[qloc];
  if (tid < 128) atomicAdd(&counts[ci], 1.0f);
  const float* crow = (ci < 512) ? (cb0 + (size_t)ci * 64) : (cb1 + (size_t)(ci - 512) * 64);
  float cv[32];
#pragma unroll
  for (int d = 0; d < 32; d += 4) {
    const float4 f = *(const float4*)(crow + dh * 32 + d);
    cv[d] = f.x; cv[d + 1] = f.y; cv[d + 2] = f.z; cv[d + 3] = f.w;
  }
  float* ob = out + (((size_t)(bb * 64 + dh * 32)) << 12) + hw0 + qloc;
#pragma unroll
  for (int d = 0; d < 32; ++d) ob[(size_t)d << 12] = cv[d];
}

__global__ void vq_final(const float* __restrict__ ws, float* __restrict__ out) {
  __shared__ float sred[256];
  const int t = threadIdx.x;
  float h = 0.f;
#pragma unroll
  for (int i = t; i < 1024; i += 256) {
    const float avg = ws[2048 + i] * (1.0f / 131072.0f);
    h += avg * logf(avg + 1e-10f);
  }
  sred[t] = h;
  __syncthreads();
  for (int s2 = 128; s2 > 0; s2 >>= 1) {
    if (t < s2) sred[t] += sred[t + s2];
    __syncthreads();
  }
  if (t == 0) {
    out[8388608] = 1.25f * ws[0] * (1.0f / 8388608.0f);
    out[8388609] = expf(-sred[0]);
  }
}

extern "C" void kernel_launch(void* const* d_in, const int* in_sizes, int n_in,
                              void* d_out, int out_size, void* d_ws, size_t ws_size,
                              hipStream_t stream) {
  (void)in_sizes; (void)n_in; (void)out_size; (void)ws_size;
  const float* xin = (const float*)d_in[0];
  const float* cb0 = (const float*)d_in[1];
  const float* cb1 = (const float*)d_in[2];
  const int* idxp = (const int*)d_in[3];
  float* out = (float*)d_out;
  float* ws = (float*)d_ws;

  vq_pack<<<4, 256, 0, stream>>>(cb0, cb1, ws);
  vq_main<<<1024, 256, 0, stream>>>(xin, cb0, cb1, idxp, out, ws);
  vq_final<<<1, 256, 0, stream>>>(ws, out);
}

// Round 6
// 120.252 us; speedup vs baseline: 1.0150x; 1.0086x over previous
//
#include <hip/hip_runtime.h>

// VQ-VAE vector quantization via bf16-split MFMA.
// score = x~.c~ where x~=[x,1,1,1]_split, c~=[c, nh0,nh1,nh2]_split (nh=-0.5||c||^2),
// computed as xh.ch + xh.cl + xl.ch (+ exact nh fold-in), err ~1e-4 absolute.
// Round 6: LDS ring buffer (3 x 20KB) + counted s_waitcnt vmcnt(5) + single
// raw s_barrier per chunk (T3+T4): prefetch spans a full chunk window, vmcnt
// never drains to 0 in steady state. M=64 per wave (256 q / block, 512 blocks
// = 2 blocks/CU exactly). B operands never occupy VGPRs (global_load_lds).
// ws layout (floats): [0] loss, [2048..3071] counts,
//   [4096..86015] packed code chunks: 16 chunks x 5120 floats (20KB), each
//   chunk = granule-major [20 granules][64 codes][16B]:
//     g 0..7  : hi bf16 dims 8g..8g+7
//     g 8     : [nh0,nh1,nh2,0...] (3-term bf16 split of -0.5||c||^2)
//     g 9     : zeros (pad dims 72..79)
//     g 10..17: lo bf16 dims 8(g-10)..
//     g 18,19 : padding (staged, never read)

typedef __attribute__((ext_vector_type(8))) short short8;
typedef __attribute__((ext_vector_type(16))) float f32x16;

#define PACKED_OFF 4096
#define CHUNK_FLOATS 5120  // 20 KB

#define GLL16(gsrc, ldst)                                                      \
  __builtin_amdgcn_global_load_lds(                                            \
      (const __attribute__((address_space(1))) void*)(gsrc),                   \
      (__attribute__((address_space(3))) void*)(ldst), 16, 0, 0)

__device__ __forceinline__ unsigned short bf16_rne(float v, float& rest) {
  const unsigned u = __float_as_uint(v);
  const unsigned r = u + 0x7fffu + ((u >> 16) & 1u);
  const unsigned short h = (unsigned short)(r >> 16);
  rest = v - __uint_as_float((unsigned)h << 16);
  return h;
}

__global__ void vq_pack(const float* __restrict__ cb0, const float* __restrict__ cb1,
                        float* __restrict__ ws) {
  const int c = blockIdx.x * 256 + threadIdx.x;  // 0..1023
  ws[2048 + c] = 0.0f;                           // counts
  if (c == 0) ws[0] = 0.0f;                      // loss
  const float* row = (c < 512) ? (cb0 + (size_t)c * 64) : (cb1 + (size_t)(c - 512) * 64);
  float v[64];
  float nrm = 0.f;
#pragma unroll
  for (int d = 0; d < 64; d += 4) {
    const float4 f = *(const float4*)(row + d);
    v[d] = f.x; v[d + 1] = f.y; v[d + 2] = f.z; v[d + 3] = f.w;
    nrm += f.x * f.x + f.y * f.y + f.z * f.z + f.w * f.w;
  }
  unsigned short hi[64], lo[64];
#pragma unroll
  for (int d = 0; d < 64; ++d) {
    float rest, dump;
    hi[d] = bf16_rne(v[d], rest);
    lo[d] = bf16_rne(rest, dump);
  }
  float* base = ws + PACKED_OFF + (size_t)(c >> 6) * CHUNK_FLOATS + (c & 63) * 4;
#pragma unroll
  for (int g = 0; g < 8; ++g) {
    short8 gr;
#pragma unroll
    for (int e = 0; e < 8; ++e) gr[e] = (short)hi[g * 8 + e];
    *(short8*)(base + g * 256) = gr;
  }
  {  // g8: nh 3-term split; g9: zeros
    const float nh = -0.5f * nrm;
    float r1, r2, dump;
    const unsigned short n0 = bf16_rne(nh, r1);
    const unsigned short n1 = bf16_rne(r1, r2);
    const unsigned short n2 = bf16_rne(r2, dump);
    short8 g8v = {(short)n0, (short)n1, (short)n2, 0, 0, 0, 0, 0};
    *(short8*)(base + 8 * 256) = g8v;
    short8 zz = {0, 0, 0, 0, 0, 0, 0, 0};
    *(short8*)(base + 9 * 256) = zz;
  }
#pragma unroll
  for (int g = 0; g < 8; ++g) {
    short8 gr;
#pragma unroll
    for (int e = 0; e < 8; ++e) gr[e] = (short)lo[g * 8 + e];
    *(short8*)(base + (10 + g) * 256) = gr;
  }
}

__global__ __launch_bounds__(256, 2) void vq_main(
    const float* __restrict__ xin, const float* __restrict__ cb0,
    const float* __restrict__ cb1, const int* __restrict__ idxp,
    float* __restrict__ out, float* __restrict__ ws) {
  __shared__ float smemf[16384];  // 64 KB: x tile, then 3x20KB B ring, then qidx
  const int tid = threadIdx.x;
  const int w = tid >> 6;      // wave 0..3, owns q rows w*64..+63
  const int l = tid & 63;
  const int half = l >> 5;
  const int col = l & 31;
  const int blk = blockIdx.x;  // 512 blocks x 256 q
  const int bb = blk >> 4;
  const int hw0 = (blk & 15) << 8;
  const int nch = (*idxp == 0) ? 8 : 16;
  float* counts = ws + 2048;

  // ---- stage x fp32 tile [d=64][q=256] into LDS (coalesced both sides)
  {
    const int qg = (tid & 63) << 2;
    const int dsub = tid >> 6;
#pragma unroll
    for (int p = 0; p < 16; ++p) {
      const int d = p * 4 + dsub;
      const float4 f = *(const float4*)(xin + (((size_t)(bb * 64 + d)) << 12) + hw0 + qg);
      *(float4*)(smemf + d * 256 + qg) = f;
    }
  }
  __syncthreads();

  // ---- extract A fragments (xh, xl) for 2 M-tiles + ||x||^2 per q-row
  short8 xh[2][4], xl[2][4];
  float xx[2];
#pragma unroll
  for (int m = 0; m < 2; ++m) {
    const int qloc = w * 64 + m * 32 + col;
    float s = 0.f;
#pragma unroll
    for (int kf = 0; kf < 4; ++kf) {
#pragma unroll
      for (int j = 0; j < 8; ++j) {
        const int d = kf * 16 + half * 8 + j;
        const float v = smemf[d * 256 + qloc];
        float rest, dump;
        xh[m][kf][j] = (short)bf16_rne(v, rest);
        xl[m][kf][j] = (short)bf16_rne(rest, dump);
        s += v * v;
      }
    }
    s += __shfl_xor(s, 32);  // lanes l, l^32: same q, complementary dims
    xx[m] = s;
  }
  // x~ extension fragment: dims 64..66 = 1.0 (hi half only)
  short8 xnh;
#pragma unroll
  for (int j = 0; j < 8; ++j)
    xnh[j] = (short)((half == 0 && j < 3) ? 0x3F80 : 0);
  const f32x16 zv = (f32x16)0.0f;  // C-input for the nh-init MFMA
  __syncthreads();  // x tile dead; B ring takes over smem

  float best[2][16];
#pragma unroll
  for (int m = 0; m < 2; ++m)
#pragma unroll
    for (int r = 0; r < 16; ++r) best[m][r] = -3.4e38f;

  char* ring = (char*)smemf;
  const char* pk = (const char*)(ws + PACKED_OFF);

  // stage one 20KB chunk: 5 global_load_lds x 1KB per wave (vmcnt +5/wave)
  auto stage = [&](int ch, int buf) {
    const char* src = pk + (size_t)ch * 20480 + w * 1024 + l * 16;
    char* dst = ring + buf * 20480 + w * 1024;
#pragma unroll
    for (int i = 0; i < 5; ++i) GLL16(src + i * 4096, dst + i * 4096);
  };

  stage(0, 0);
  stage(1, 1);
  for (int ch = 0; ch < nch; ++ch) {
    __builtin_amdgcn_sched_barrier(0);  // pin prior chunk's work above the wait
    if (ch < nch - 1) {
      asm volatile("s_waitcnt vmcnt(5)" ::: "memory");  // ch's 5 DMAs done
    } else {
      asm volatile("s_waitcnt vmcnt(0)" ::: "memory");
    }
    __builtin_amdgcn_s_barrier();  // raw barrier: no implicit drain
    if (ch + 2 < nch) stage(ch + 2, (ch + 2) % 3);  // refills buf[(ch-1)%3]
    const char* bufp = ring + (ch % 3) * 20480;
    const int cb = col * 16;

    // fragment loads: granule-major => two contiguous 512B regions per read
    __builtin_amdgcn_s_setprio(1);
    // nh init: kf=4 hi fragment with C = zero vector (no mov-init of acc)
    const short8 bn0 = *(const short8*)(bufp + (8 + half) * 1024 + cb);
    const short8 bn1 = *(const short8*)(bufp + (8 + half) * 1024 + 512 + cb);
    f32x16 a00 = __builtin_amdgcn_mfma_f32_32x32x16_bf16(xnh, bn0, zv, 0, 0, 0);
    f32x16 a01 = __builtin_amdgcn_mfma_f32_32x32x16_bf16(xnh, bn1, zv, 0, 0, 0);
    f32x16 a10 = __builtin_amdgcn_mfma_f32_32x32x16_bf16(xnh, bn0, zv, 0, 0, 0);
    f32x16 a11 = __builtin_amdgcn_mfma_f32_32x32x16_bf16(xnh, bn1, zv, 0, 0, 0);
#pragma unroll
    for (int kf = 0; kf < 4; ++kf) {
      const char* ph = bufp + (2 * kf + half) * 1024 + cb;
      const char* pl = bufp + (10 + 2 * kf + half) * 1024 + cb;
      const short8 bh0 = *(const short8*)(ph);
      const short8 bh1 = *(const short8*)(ph + 512);
      const short8 bl0 = *(const short8*)(pl);
      const short8 bl1 = *(const short8*)(pl + 512);
      a00 = __builtin_amdgcn_mfma_f32_32x32x16_bf16(xh[0][kf], bh0, a00, 0, 0, 0);
      a01 = __builtin_amdgcn_mfma_f32_32x32x16_bf16(xh[0][kf], bh1, a01, 0, 0, 0);
      a10 = __builtin_amdgcn_mfma_f32_32x32x16_bf16(xh[1][kf], bh0, a10, 0, 0, 0);
      a11 = __builtin_amdgcn_mfma_f32_32x32x16_bf16(xh[1][kf], bh1, a11, 0, 0, 0);
      a00 = __builtin_amdgcn_mfma_f32_32x32x16_bf16(xh[0][kf], bl0, a00, 0, 0, 0);
      a01 = __builtin_amdgcn_mfma_f32_32x32x16_bf16(xh[0][kf], bl1, a01, 0, 0, 0);
      a10 = __builtin_amdgcn_mfma_f32_32x32x16_bf16(xh[1][kf], bl0, a10, 0, 0, 0);
      a11 = __builtin_amdgcn_mfma_f32_32x32x16_bf16(xh[1][kf], bl1, a11, 0, 0, 0);
      a00 = __builtin_amdgcn_mfma_f32_32x32x16_bf16(xl[0][kf], bh0, a00, 0, 0, 0);
      a01 = __builtin_amdgcn_mfma_f32_32x32x16_bf16(xl[0][kf], bh1, a01, 0, 0, 0);
      a10 = __builtin_amdgcn_mfma_f32_32x32x16_bf16(xl[1][kf], bh0, a10, 0, 0, 0);
      a11 = __builtin_amdgcn_mfma_f32_32x32x16_bf16(xl[1][kf], bh1, a11, 0, 0, 0);
    }
    __builtin_amdgcn_s_setprio(0);

    // ---- running argmax; code id (ch*2+n, inverted) packed in mantissa LSBs
    const unsigned sid0 = (unsigned)(31 - 2 * ch);
    const unsigned sid1 = (unsigned)(30 - 2 * ch);
#pragma unroll
    for (int r = 0; r < 16; ++r) {
      const unsigned p00 = (__float_as_uint(a00[r]) & 0xFFFFFFE0u) | sid0;
      const unsigned p01 = (__float_as_uint(a01[r]) & 0xFFFFFFE0u) | sid1;
      best[0][r] = fmaxf(best[0][r], fmaxf(__uint_as_float(p00), __uint_as_float(p01)));
      const unsigned p10 = (__float_as_uint(a10[r]) & 0xFFFFFFE0u) | sid0;
      const unsigned p11 = (__float_as_uint(a11[r]) & 0xFFFFFFE0u) | sid1;
      best[1][r] = fmaxf(best[1][r], fmaxf(__uint_as_float(p10), __uint_as_float(p11)));
    }
  }
  __syncthreads();  // all ds_reads done; ring reusable as qidx

  // ---- cross-lane argmax reduce (within 32-lane half), first-index ties
  int* qidx = (int*)smemf;  // [256]
  float ls = 0.f;
#pragma unroll
  for (int m = 0; m < 2; ++m) {
#pragma unroll
    for (int r = 0; r < 16; ++r) {
      float v = best[m][r];
      int idx = (int)(31u - (__float_as_uint(v) & 31u)) * 32 + col;
#pragma unroll
      for (int mk = 1; mk < 32; mk <<= 1) {
        const float ov = __shfl_xor(v, mk);
        const int oi = __shfl_xor(idx, mk);
        if (ov > v || (ov == v && oi < idx)) { v = ov; idx = oi; }
      }
      const int row = (r & 3) + 8 * (r >> 2) + 4 * half;  // C layout row
      if (col == row) {
        const float vc = __uint_as_float(__float_as_uint(v) & 0xFFFFFFE0u);
        ls += xx[m] - 2.0f * vc;  // ||x||^2 - 2(x.c* - 0.5||c*||^2)
        qidx[w * 64 + m * 32 + row] = idx;
      }
    }
  }
#pragma unroll
  for (int mk = 1; mk < 64; mk <<= 1) ls += __shfl_xor(ls, mk);
  if (l == 0) atomicAdd(ws, ls);
  __syncthreads();

  // ---- histogram + quantized output (NCHW, coalesced stores; codes L2-hot)
  const int ci = qidx[tid];
  atomicAdd(&counts[ci], 1.0f);
  const float* crow = (ci < 512) ? (cb0 + (size_t)ci * 64) : (cb1 + (size_t)(ci - 512) * 64);
  float cv[64];
#pragma unroll
  for (int d = 0; d < 64; d += 4) {
    const float4 f = *(const float4*)(crow + d);
    cv[d] = f.x; cv[d + 1] = f.y; cv[d + 2] = f.z; cv[d + 3] = f.w;
  }
  float* ob = out + (((size_t)(bb * 64)) << 12) + hw0 + tid;
#pragma unroll
  for (int d = 0; d < 64; ++d) ob[(size_t)d << 12] = cv[d];
}

__global__ void vq_final(const float* __restrict__ ws, float* __restrict__ out) {
  __shared__ float sred[256];
  const int t = threadIdx.x;
  float h = 0.f;
#pragma unroll
  for (int i = t; i < 1024; i += 256) {
    const float avg = ws[2048 + i] * (1.0f / 131072.0f);
    h += avg * logf(avg + 1e-10f);
  }
  sred[t] = h;
  __syncthreads();
  for (int s2 = 128; s2 > 0; s2 >>= 1) {
    if (t < s2) sred[t] += sred[t + s2];
    __syncthreads();
  }
  if (t == 0) {
    out[8388608] = 1.25f * ws[0] * (1.0f / 8388608.0f);
    out[8388609] = expf(-sred[0]);
  }
}

extern "C" void kernel_launch(void* const* d_in, const int* in_sizes, int n_in,
                              void* d_out, int out_size, void* d_ws, size_t ws_size,
                              hipStream_t stream) {
  (void)in_sizes; (void)n_in; (void)out_size; (void)ws_size;
  const float* xin = (const float*)d_in[0];
  const float* cb0 = (const float*)d_in[1];
  const float* cb1 = (const float*)d_in[2];
  const int* idxp = (const int*)d_in[3];
  float* out = (float*)d_out;
  float* ws = (float*)d_ws;

  vq_pack<<<4, 256, 0, stream>>>(cb0, cb1, ws);
  vq_main<<<512, 256, 0, stream>>>(xin, cb0, cb1, idxp, out, ws);
  vq_final<<<1, 256, 0, stream>>>(ws, out);
}

// Round 7
// 101.800 us; speedup vs baseline: 1.1989x; 1.1813x over previous
//
#include <hip/hip_runtime.h>

// VQ-VAE vector quantization via bf16-split MFMA.
// score = x~.c~ where x~=[x,1,1,1]_split, c~=[c, nh0,nh1,nh2]_split (nh=-0.5||c||^2),
// computed as xh.ch + xh.cl + xl.ch (+ exact nh fold-in), err ~1e-4 absolute.
// Round 7: SAME K-loop as round 6 (LDS ring 3x20KB, counted vmcnt, raw barrier).
// ONLY change: histogram privatized into 32 partial histograms to kill the
// end-of-kernel burst of 131k same-line device-scope atomics (round-6 theory:
// that burst serializes ~50+us at the coherent point; every pipe <20% busy).
// ws layout (floats): [0] loss, [1024..33791] 32 x 1024 partial counts,
//   [34816..116735] packed code chunks: 16 chunks x 5120 floats (20KB), each
//   chunk = granule-major [20 granules][64 codes][16B]:
//     g 0..7  : hi bf16 dims 8g..8g+7
//     g 8     : [nh0,nh1,nh2,0...] (3-term bf16 split of -0.5||c||^2)
//     g 9     : zeros (pad dims 72..79)
//     g 10..17: lo bf16 dims 8(g-10)..
//     g 18,19 : padding (staged, never read)

typedef __attribute__((ext_vector_type(8))) short short8;
typedef __attribute__((ext_vector_type(16))) float f32x16;

#define PART_OFF 1024
#define NPART 32
#define PACKED_OFF 34816
#define CHUNK_FLOATS 5120  // 20 KB

#define GLL16(gsrc, ldst)                                                      \
  __builtin_amdgcn_global_load_lds(                                            \
      (const __attribute__((address_space(1))) void*)(gsrc),                   \
      (__attribute__((address_space(3))) void*)(ldst), 16, 0, 0)

__device__ __forceinline__ unsigned short bf16_rne(float v, float& rest) {
  const unsigned u = __float_as_uint(v);
  const unsigned r = u + 0x7fffu + ((u >> 16) & 1u);
  const unsigned short h = (unsigned short)(r >> 16);
  rest = v - __uint_as_float((unsigned)h << 16);
  return h;
}

__global__ void vq_pack(const float* __restrict__ cb0, const float* __restrict__ cb1,
                        float* __restrict__ ws) {
  const int c = blockIdx.x * 256 + threadIdx.x;  // 0..1023
#pragma unroll
  for (int p = 0; p < NPART; ++p) ws[PART_OFF + p * 1024 + c] = 0.0f;
  if (c == 0) ws[0] = 0.0f;  // loss
  const float* row = (c < 512) ? (cb0 + (size_t)c * 64) : (cb1 + (size_t)(c - 512) * 64);
  float v[64];
  float nrm = 0.f;
#pragma unroll
  for (int d = 0; d < 64; d += 4) {
    const float4 f = *(const float4*)(row + d);
    v[d] = f.x; v[d + 1] = f.y; v[d + 2] = f.z; v[d + 3] = f.w;
    nrm += f.x * f.x + f.y * f.y + f.z * f.z + f.w * f.w;
  }
  unsigned short hi[64], lo[64];
#pragma unroll
  for (int d = 0; d < 64; ++d) {
    float rest, dump;
    hi[d] = bf16_rne(v[d], rest);
    lo[d] = bf16_rne(rest, dump);
  }
  float* base = ws + PACKED_OFF + (size_t)(c >> 6) * CHUNK_FLOATS + (c & 63) * 4;
#pragma unroll
  for (int g = 0; g < 8; ++g) {
    short8 gr;
#pragma unroll
    for (int e = 0; e < 8; ++e) gr[e] = (short)hi[g * 8 + e];
    *(short8*)(base + g * 256) = gr;
  }
  {  // g8: nh 3-term split; g9: zeros
    const float nh = -0.5f * nrm;
    float r1, r2, dump;
    const unsigned short n0 = bf16_rne(nh, r1);
    const unsigned short n1 = bf16_rne(r1, r2);
    const unsigned short n2 = bf16_rne(r2, dump);
    short8 g8v = {(short)n0, (short)n1, (short)n2, 0, 0, 0, 0, 0};
    *(short8*)(base + 8 * 256) = g8v;
    short8 zz = {0, 0, 0, 0, 0, 0, 0, 0};
    *(short8*)(base + 9 * 256) = zz;
  }
#pragma unroll
  for (int g = 0; g < 8; ++g) {
    short8 gr;
#pragma unroll
    for (int e = 0; e < 8; ++e) gr[e] = (short)lo[g * 8 + e];
    *(short8*)(base + (10 + g) * 256) = gr;
  }
}

__global__ __launch_bounds__(256, 2) void vq_main(
    const float* __restrict__ xin, const float* __restrict__ cb0,
    const float* __restrict__ cb1, const int* __restrict__ idxp,
    float* __restrict__ out, float* __restrict__ ws) {
  __shared__ float smemf[16384];  // 64 KB: x tile, then 3x20KB B ring, then qidx
  const int tid = threadIdx.x;
  const int w = tid >> 6;      // wave 0..3, owns q rows w*64..+63
  const int l = tid & 63;
  const int half = l >> 5;
  const int col = l & 31;
  const int blk = blockIdx.x;  // 512 blocks x 256 q
  const int bb = blk >> 4;
  const int hw0 = (blk & 15) << 8;
  const int nch = (*idxp == 0) ? 8 : 16;
  float* parts = ws + PART_OFF + (size_t)(blk & (NPART - 1)) * 1024;

  // ---- stage x fp32 tile [d=64][q=256] into LDS (coalesced both sides)
  {
    const int qg = (tid & 63) << 2;
    const int dsub = tid >> 6;
#pragma unroll
    for (int p = 0; p < 16; ++p) {
      const int d = p * 4 + dsub;
      const float4 f = *(const float4*)(xin + (((size_t)(bb * 64 + d)) << 12) + hw0 + qg);
      *(float4*)(smemf + d * 256 + qg) = f;
    }
  }
  __syncthreads();

  // ---- extract A fragments (xh, xl) for 2 M-tiles + ||x||^2 per q-row
  short8 xh[2][4], xl[2][4];
  float xx[2];
#pragma unroll
  for (int m = 0; m < 2; ++m) {
    const int qloc = w * 64 + m * 32 + col;
    float s = 0.f;
#pragma unroll
    for (int kf = 0; kf < 4; ++kf) {
#pragma unroll
      for (int j = 0; j < 8; ++j) {
        const int d = kf * 16 + half * 8 + j;
        const float v = smemf[d * 256 + qloc];
        float rest, dump;
        xh[m][kf][j] = (short)bf16_rne(v, rest);
        xl[m][kf][j] = (short)bf16_rne(rest, dump);
        s += v * v;
      }
    }
    s += __shfl_xor(s, 32);  // lanes l, l^32: same q, complementary dims
    xx[m] = s;
  }
  // x~ extension fragment: dims 64..66 = 1.0 (hi half only)
  short8 xnh;
#pragma unroll
  for (int j = 0; j < 8; ++j)
    xnh[j] = (short)((half == 0 && j < 3) ? 0x3F80 : 0);
  const f32x16 zv = (f32x16)0.0f;  // C-input for the nh-init MFMA
  __syncthreads();  // x tile dead; B ring takes over smem

  float best[2][16];
#pragma unroll
  for (int m = 0; m < 2; ++m)
#pragma unroll
    for (int r = 0; r < 16; ++r) best[m][r] = -3.4e38f;

  char* ring = (char*)smemf;
  const char* pk = (const char*)(ws + PACKED_OFF);

  // stage one 20KB chunk: 5 global_load_lds x 1KB per wave (vmcnt +5/wave)
  auto stage = [&](int ch, int buf) {
    const char* src = pk + (size_t)ch * 20480 + w * 1024 + l * 16;
    char* dst = ring + buf * 20480 + w * 1024;
#pragma unroll
    for (int i = 0; i < 5; ++i) GLL16(src + i * 4096, dst + i * 4096);
  };

  stage(0, 0);
  stage(1, 1);
  for (int ch = 0; ch < nch; ++ch) {
    __builtin_amdgcn_sched_barrier(0);  // pin prior chunk's work above the wait
    if (ch < nch - 1) {
      asm volatile("s_waitcnt vmcnt(5)" ::: "memory");  // ch's 5 DMAs done
    } else {
      asm volatile("s_waitcnt vmcnt(0)" ::: "memory");
    }
    __builtin_amdgcn_s_barrier();  // raw barrier: no implicit drain
    if (ch + 2 < nch) stage(ch + 2, (ch + 2) % 3);  // refills buf[(ch-1)%3]
    const char* bufp = ring + (ch % 3) * 20480;
    const int cb = col * 16;

    // fragment loads: granule-major => two contiguous 512B regions per read
    __builtin_amdgcn_s_setprio(1);
    // nh init: kf=4 hi fragment with C = zero vector (no mov-init of acc)
    const short8 bn0 = *(const short8*)(bufp + (8 + half) * 1024 + cb);
    const short8 bn1 = *(const short8*)(bufp + (8 + half) * 1024 + 512 + cb);
    f32x16 a00 = __builtin_amdgcn_mfma_f32_32x32x16_bf16(xnh, bn0, zv, 0, 0, 0);
    f32x16 a01 = __builtin_amdgcn_mfma_f32_32x32x16_bf16(xnh, bn1, zv, 0, 0, 0);
    f32x16 a10 = __builtin_amdgcn_mfma_f32_32x32x16_bf16(xnh, bn0, zv, 0, 0, 0);
    f32x16 a11 = __builtin_amdgcn_mfma_f32_32x32x16_bf16(xnh, bn1, zv, 0, 0, 0);
#pragma unroll
    for (int kf = 0; kf < 4; ++kf) {
      const char* ph = bufp + (2 * kf + half) * 1024 + cb;
      const char* pl = bufp + (10 + 2 * kf + half) * 1024 + cb;
      const short8 bh0 = *(const short8*)(ph);
      const short8 bh1 = *(const short8*)(ph + 512);
      const short8 bl0 = *(const short8*)(pl);
      const short8 bl1 = *(const short8*)(pl + 512);
      a00 = __builtin_amdgcn_mfma_f32_32x32x16_bf16(xh[0][kf], bh0, a00, 0, 0, 0);
      a01 = __builtin_amdgcn_mfma_f32_32x32x16_bf16(xh[0][kf], bh1, a01, 0, 0, 0);
      a10 = __builtin_amdgcn_mfma_f32_32x32x16_bf16(xh[1][kf], bh0, a10, 0, 0, 0);
      a11 = __builtin_amdgcn_mfma_f32_32x32x16_bf16(xh[1][kf], bh1, a11, 0, 0, 0);
      a00 = __builtin_amdgcn_mfma_f32_32x32x16_bf16(xh[0][kf], bl0, a00, 0, 0, 0);
      a01 = __builtin_amdgcn_mfma_f32_32x32x16_bf16(xh[0][kf], bl1, a01, 0, 0, 0);
      a10 = __builtin_amdgcn_mfma_f32_32x32x16_bf16(xh[1][kf], bl0, a10, 0, 0, 0);
      a11 = __builtin_amdgcn_mfma_f32_32x32x16_bf16(xh[1][kf], bl1, a11, 0, 0, 0);
      a00 = __builtin_amdgcn_mfma_f32_32x32x16_bf16(xl[0][kf], bh0, a00, 0, 0, 0);
      a01 = __builtin_amdgcn_mfma_f32_32x32x16_bf16(xl[0][kf], bh1, a01, 0, 0, 0);
      a10 = __builtin_amdgcn_mfma_f32_32x32x16_bf16(xl[1][kf], bh0, a10, 0, 0, 0);
      a11 = __builtin_amdgcn_mfma_f32_32x32x16_bf16(xl[1][kf], bh1, a11, 0, 0, 0);
    }
    __builtin_amdgcn_s_setprio(0);

    // ---- running argmax; code id (ch*2+n, inverted) packed in mantissa LSBs
    const unsigned sid0 = (unsigned)(31 - 2 * ch);
    const unsigned sid1 = (unsigned)(30 - 2 * ch);
#pragma unroll
    for (int r = 0; r < 16; ++r) {
      const unsigned p00 = (__float_as_uint(a00[r]) & 0xFFFFFFE0u) | sid0;
      const unsigned p01 = (__float_as_uint(a01[r]) & 0xFFFFFFE0u) | sid1;
      best[0][r] = fmaxf(best[0][r], fmaxf(__uint_as_float(p00), __uint_as_float(p01)));
      const unsigned p10 = (__float_as_uint(a10[r]) & 0xFFFFFFE0u) | sid0;
      const unsigned p11 = (__float_as_uint(a11[r]) & 0xFFFFFFE0u) | sid1;
      best[1][r] = fmaxf(best[1][r], fmaxf(__uint_as_float(p10), __uint_as_float(p11)));
    }
  }
  __syncthreads();  // all ds_reads done; ring reusable as qidx

  // ---- cross-lane argmax reduce (within 32-lane half), first-index ties
  int* qidx = (int*)smemf;  // [256]
  float ls = 0.f;
#pragma unroll
  for (int m = 0; m < 2; ++m) {
#pragma unroll
    for (int r = 0; r < 16; ++r) {
      float v = best[m][r];
      int idx = (int)(31u - (__float_as_uint(v) & 31u)) * 32 + col;
#pragma unroll
      for (int mk = 1; mk < 32; mk <<= 1) {
        const float ov = __shfl_xor(v, mk);
        const int oi = __shfl_xor(idx, mk);
        if (ov > v || (ov == v && oi < idx)) { v = ov; idx = oi; }
      }
      const int row = (r & 3) + 8 * (r >> 2) + 4 * half;  // C layout row
      if (col == row) {
        const float vc = __uint_as_float(__float_as_uint(v) & 0xFFFFFFE0u);
        ls += xx[m] - 2.0f * vc;  // ||x||^2 - 2(x.c* - 0.5||c*||^2)
        qidx[w * 64 + m * 32 + row] = idx;
      }
    }
  }
#pragma unroll
  for (int mk = 1; mk < 64; mk <<= 1) ls += __shfl_xor(ls, mk);
  if (l == 0) atomicAdd(ws, ls);
  __syncthreads();

  // ---- histogram (32-way partial, low contention) + quantized output
  const int ci = qidx[tid];
  atomicAdd(&parts[ci], 1.0f);
  const float* crow = (ci < 512) ? (cb0 + (size_t)ci * 64) : (cb1 + (size_t)(ci - 512) * 64);
  float cv[64];
#pragma unroll
  for (int d = 0; d < 64; d += 4) {
    const float4 f = *(const float4*)(crow + d);
    cv[d] = f.x; cv[d + 1] = f.y; cv[d + 2] = f.z; cv[d + 3] = f.w;
  }
  float* ob = out + (((size_t)(bb * 64)) << 12) + hw0 + tid;
#pragma unroll
  for (int d = 0; d < 64; ++d) ob[(size_t)d << 12] = cv[d];
}

__global__ void vq_final(const float* __restrict__ ws, float* __restrict__ out) {
  __shared__ float sred[256];
  const int t = threadIdx.x;
  float h = 0.f;
#pragma unroll
  for (int i = t; i < 1024; i += 256) {
    float s = 0.f;
#pragma unroll
    for (int p = 0; p < NPART; ++p) s += ws[PART_OFF + p * 1024 + i];
    const float avg = s * (1.0f / 131072.0f);
    h += avg * logf(avg + 1e-10f);
  }
  sred[t] = h;
  __syncthreads();
  for (int s2 = 128; s2 > 0; s2 >>= 1) {
    if (t < s2) sred[t] += sred[t + s2];
    __syncthreads();
  }
  if (t == 0) {
    out[8388608] = 1.25f * ws[0] * (1.0f / 8388608.0f);
    out[8388609] = expf(-sred[0]);
  }
}

extern "C" void kernel_launch(void* const* d_in, const int* in_sizes, int n_in,
                              void* d_out, int out_size, void* d_ws, size_t ws_size,
                              hipStream_t stream) {
  (void)in_sizes; (void)n_in; (void)out_size; (void)ws_size;
  const float* xin = (const float*)d_in[0];
  const float* cb0 = (const float*)d_in[1];
  const float* cb1 = (const float*)d_in[2];
  const int* idxp = (const int*)d_in[3];
  float* out = (float*)d_out;
  float* ws = (float*)d_ws;

  vq_pack<<<4, 256, 0, stream>>>(cb0, cb1, ws);
  vq_main<<<512, 256, 0, stream>>>(xin, cb0, cb1, idxp, out, ws);
  vq_final<<<1, 256, 0, stream>>>(ws, out);
}